// Round 21
// baseline (1284.374 us; speedup 1.0000x reference)
//
#include <hip/hip_runtime.h>
#include <hip/hip_bf16.h>
#include <string.h>

#define NNODES 50000
#define TSTEPS 8
#define NEDGES 800000
#define VVOCAB 1000
#define DDIM 32
#define HDIM 128
#define G0DIM 64
#define H3 384
#define NSB 4          // src blocks: key = dst*NSB + src/SRCBLK
#define SRCBLK 12500
#define NKEY (NNODES * NSB)      // 200000 keys per timestep
#define NBLK 64                  // edge blocks per timestep for the sort
#define EPB 12500                // edges per block (64*12500 = 800000 exactly)
#define COARSE 391               // coarse bins = key>>9 (max key 199999 -> 390)
#define FINEN 512                // fine keys per coarse bin (key & 511)
#define NSCN (COARSE * NBLK)     // 25024
#define NCHK2 49                 // ceil(NSCN/512)
#define STAGE_CAP 4096           // LDS staging capacity for fine_sort bins

typedef _Float16 v8h __attribute__((ext_vector_type(8)));
typedef float v4f __attribute__((ext_vector_type(4)));

__device__ __forceinline__ float w_decode(unsigned int packed) {
  unsigned short wb = (unsigned short)(packed >> 16);
  _Float16 h;
  __builtin_memcpy(&h, &wb, 2);
  return (float)h;
}

// ============== Atomic-free two-level counting sort (CSR build) ===========================

// A1: per-block LDS histogram + in-block exclusive scan -> bh (counts) + blofs (local offs)
__global__ __launch_bounds__(512) void coarse_hist(const int* __restrict__ edges,
                                                   int* __restrict__ bh,
                                                   int* __restrict__ blofs) {
  __shared__ int hist[COARSE];
  __shared__ int sbuf[COARSE];
  int t = blockIdx.y, b = blockIdx.x, tid = threadIdx.x;
  for (int i = tid; i < COARSE; i += 512) hist[i] = 0;
  __syncthreads();
  const int* srcp = edges + (size_t)t * 2 * NEDGES + (size_t)b * EPB;
  const int* dstp = srcp + NEDGES;
  for (int i = tid; i < EPB; i += 512) {
    int key = dstp[i] * NSB + srcp[i] / SRCBLK;
    atomicAdd(&hist[key >> 9], 1);
  }
  __syncthreads();
  if (tid < COARSE) sbuf[tid] = hist[tid];
  __syncthreads();
  for (int d = 1; d < COARSE; d <<= 1) {
    int v = 0;
    if (tid < COARSE && tid >= d) v = sbuf[tid - d];
    __syncthreads();
    if (tid < COARSE) sbuf[tid] += v;
    __syncthreads();
  }
  if (tid < COARSE) {
    bh[(size_t)t * NSCN + tid * NBLK + b] = hist[tid];
    blofs[((size_t)t * NBLK + b) * COARSE + tid] = sbuf[tid] - hist[tid];  // exclusive
  }
}

// global scan of bh -> bscan (per-(coarse,block) global output bases)
__global__ __launch_bounds__(256) void scan_c1(const int* __restrict__ bh,
                                               int* __restrict__ csum) {
  int bid = blockIdx.x;  // t*NCHK2 + c
  int t = bid / NCHK2, c = bid % NCHK2;
  int tid = threadIdx.x;
  int s = 0;
#pragma unroll
  for (int i = 0; i < 2; ++i) {
    int n = c * 512 + tid + i * 256;
    if (n < NSCN) s += bh[(size_t)t * NSCN + n];
  }
#pragma unroll
  for (int off = 32; off > 0; off >>= 1) s += __shfl_down(s, off, 64);
  __shared__ int wsum[4];
  if ((tid & 63) == 0) wsum[tid >> 6] = s;
  __syncthreads();
  if (tid == 0) csum[bid] = wsum[0] + wsum[1] + wsum[2] + wsum[3];
}

__global__ __launch_bounds__(512) void scan_c2(const int* __restrict__ csum,
                                               int* __restrict__ cbase) {
  int t = blockIdx.x;
  int tid = threadIdx.x;
  __shared__ int buf[512];
  int own = (tid < NCHK2) ? csum[t * NCHK2 + tid] : 0;
  buf[tid] = own;
  __syncthreads();
  for (int d = 1; d < 512; d <<= 1) {
    int v = (tid >= d) ? buf[tid - d] : 0;
    __syncthreads();
    buf[tid] += v;
    __syncthreads();
  }
  if (tid < NCHK2) cbase[t * NCHK2 + tid] = buf[tid] - own;
}

__global__ __launch_bounds__(512) void scan_c3(const int* __restrict__ bh,
                                               const int* __restrict__ cbase,
                                               int* __restrict__ bscan) {
  int bid = blockIdx.x;
  int t = bid / NCHK2, c = bid % NCHK2;
  int tid = threadIdx.x;
  int n = c * 512 + tid;
  int d = (n < NSCN) ? bh[(size_t)t * NSCN + n] : 0;
  __shared__ int buf[512];
  buf[tid] = d;
  __syncthreads();
  for (int s = 1; s < 512; s <<= 1) {
    int v = (tid >= s) ? buf[tid - s] : 0;
    __syncthreads();
    buf[tid] += v;
    __syncthreads();
  }
  if (n < NSCN) bscan[(size_t)t * NSCN + n] = cbase[bid] + buf[tid] - d;
}

// A3: BLOCK-LOCAL scatter: each block sorts its edges into its own contiguous 100KB
// window [b*EPB, (b+1)*EPB) ordered by coarse bin -> ~1x write amplification.
__global__ __launch_bounds__(512) void coarse_scatter(
    const int* __restrict__ edges, const float* __restrict__ weights,
    const int* __restrict__ blofs, int2* __restrict__ tmp) {
  __shared__ int cur[COARSE];
  int t = blockIdx.y, b = blockIdx.x, tid = threadIdx.x;
  for (int i = tid; i < COARSE; i += 512)
    cur[i] = b * EPB + blofs[((size_t)t * NBLK + b) * COARSE + i];
  __syncthreads();
  const int* srcp = edges + (size_t)t * 2 * NEDGES + (size_t)b * EPB;
  const int* dstp = srcp + NEDGES;
  const float* wp = weights + (size_t)t * NEDGES + (size_t)b * EPB;
  for (int i = tid; i < EPB; i += 512) {
    int src = srcp[i];
    int key = dstp[i] * NSB + src / SRCBLK;
    int coarse = key >> 9, fine = key & 511;
    int pos = atomicAdd(&cur[coarse], 1);  // LDS atomic; pos within block window
    int2 pk;
    pk.x = src | (fine << 16);
    pk.y = __float_as_int(wp[i]);
    tmp[(size_t)t * NEDGES + pos] = pk;
  }
}

// B: per (t,coarse) bin: gather 64 block segments (1 wave each) into LDS, LDS counting
// sort over 512 fine keys, coalesced packed-4B output + offs.
__global__ __launch_bounds__(512) void fine_sort(
    const int* __restrict__ bscan, const int* __restrict__ bh,
    const int* __restrict__ blofs, const int2* __restrict__ tmp,
    unsigned int* __restrict__ csr, int* __restrict__ offs) {
  __shared__ int fhist[FINEN], fbase[FINEN], fcur[FINEN], buf[FINEN];
  __shared__ int2 binbuf[STAGE_CAP];
  __shared__ unsigned int outstage[STAGE_CAP];
  __shared__ int cnts[NBLK], rel[NBLK], lseg[NBLK];
  int t = blockIdx.y, coarse = blockIdx.x, tid = threadIdx.x;
  int cb0 = bscan[(size_t)t * NSCN + coarse * NBLK];
  int cb1 = (coarse == COARSE - 1) ? NEDGES : bscan[(size_t)t * NSCN + (coarse + 1) * NBLK];
  int size = cb1 - cb0;
  fhist[tid] = 0;
  fcur[tid] = 0;
  if (tid < NBLK) {
    cnts[tid] = bh[(size_t)t * NSCN + coarse * NBLK + tid];
    rel[tid] = bscan[(size_t)t * NSCN + coarse * NBLK + tid] - cb0;
    lseg[tid] = blofs[((size_t)t * NBLK + tid) * COARSE + coarse];
  }
  __syncthreads();
  int wv = tid >> 6, ln = tid & 63;
  bool staged = (size <= STAGE_CAP);
  if (staged) {
    // gather segments into LDS (one wave per segment, coalesced bursts)
    for (int b = wv; b < NBLK; b += 8) {
      int c = cnts[b];
      const int2* seg = tmp + (size_t)t * NEDGES + (size_t)b * EPB + lseg[b];
      int rb = rel[b];
      for (int j = ln; j < c; j += 64) binbuf[rb + j] = seg[j];
    }
    __syncthreads();
    for (int i = tid; i < size; i += 512)
      atomicAdd(&fhist[(binbuf[i].x >> 16) & 511], 1);
  } else {
    for (int b = wv; b < NBLK; b += 8) {
      int c = cnts[b];
      const int2* seg = tmp + (size_t)t * NEDGES + (size_t)b * EPB + lseg[b];
      for (int j = ln; j < c; j += 64)
        atomicAdd(&fhist[(seg[j].x >> 16) & 511], 1);
    }
  }
  __syncthreads();
  buf[tid] = fhist[tid];
  __syncthreads();
  for (int d = 1; d < FINEN; d <<= 1) {
    int v = (tid >= d) ? buf[tid - d] : 0;
    __syncthreads();
    buf[tid] += v;
    __syncthreads();
  }
  fbase[tid] = buf[tid] - fhist[tid];
  int key = coarse * FINEN + tid;
  if (key < NKEY) offs[(size_t)t * (NKEY + 1) + key] = cb0 + fbase[tid];
  if (coarse == COARSE - 1 && tid == 0) offs[(size_t)t * (NKEY + 1) + NKEY] = NEDGES;
  __syncthreads();
  unsigned int* outp = csr + (size_t)t * NEDGES + cb0;
  if (staged) {
    for (int i = tid; i < size; i += 512) {
      int2 p = binbuf[i];
      int fine = (p.x >> 16) & 511;
      int lr = atomicAdd(&fcur[fine], 1);  // LDS atomic
      _Float16 wh = (_Float16)__int_as_float(p.y);
      unsigned short wb;
      __builtin_memcpy(&wb, &wh, 2);
      outstage[fbase[fine] + lr] = (unsigned int)(p.x & 0xFFFF) | ((unsigned int)wb << 16);
    }
    __syncthreads();
    for (int i = tid; i < size; i += 512) outp[i] = outstage[i];
  } else {
    for (int b = wv; b < NBLK; b += 8) {
      int c = cnts[b];
      const int2* seg = tmp + (size_t)t * NEDGES + (size_t)b * EPB + lseg[b];
      for (int j = ln; j < c; j += 64) {
        int2 p = seg[j];
        int fine = (p.x >> 16) & 511;
        int lr = atomicAdd(&fcur[fine], 1);
        _Float16 wh = (_Float16)__int_as_float(p.y);
        unsigned short wb;
        __builtin_memcpy(&wb, &wh, 2);
        outp[fbase[fine] + lr] = (unsigned int)(p.x & 0xFFFF) | ((unsigned int)wb << 16);
      }
    }
  }
}

// ============== Gathers (4B packed csr entries) ===========================================

template <int D>
__global__ __launch_bounds__(256) void gather_merged(
    const int* __restrict__ off, const unsigned int* __restrict__ csr,
    const _Float16* __restrict__ x, _Float16* __restrict__ m) {
  const int LPN = D / 8;
  int n = blockIdx.x * (256 / LPN) + threadIdx.x / LPN;
  int l = threadIdx.x % LPN;
  if (n >= NNODES) return;
  int s0 = off[n * NSB], s1 = off[(n + 1) * NSB];
  float a0[8], a1[8];
#pragma unroll
  for (int i = 0; i < 8; ++i) { a0[i] = 0.f; a1[i] = 0.f; }
  int e = s0;
  for (; e + 1 < s1; e += 2) {
    unsigned int eA = csr[e], eB = csr[e + 1];
    v8h xA = *(const v8h*)&x[(size_t)(eA & 0xFFFF) * D + l * 8];
    v8h xB = *(const v8h*)&x[(size_t)(eB & 0xFFFF) * D + l * 8];
    float wA = w_decode(eA), wB = w_decode(eB);
#pragma unroll
    for (int i = 0; i < 8; ++i) {
      a0[i] += wA * (float)xA[i];
      a1[i] += wB * (float)xB[i];
    }
  }
  if (e < s1) {
    unsigned int eA = csr[e];
    v8h xA = *(const v8h*)&x[(size_t)(eA & 0xFFFF) * D + l * 8];
    float wA = w_decode(eA);
#pragma unroll
    for (int i = 0; i < 8; ++i) a0[i] += wA * (float)xA[i];
  }
  v8h r;
#pragma unroll
  for (int i = 0; i < 8; ++i) r[i] = (_Float16)(a0[i] + a1[i]);
  *(v8h*)&m[(size_t)n * D + l * 8] = r;
}

// ============== Dense kernels =============================================================

__global__ __launch_bounds__(384) void fuse_w(
    const float* __restrict__ gW2, const float* __restrict__ Wx, float* __restrict__ Wf) {
  int t = blockIdx.x >> 7;
  int k = blockIdx.x & 127;
  int j = threadIdx.x;
  __shared__ float row[HDIM];
  if (j < HDIM) row[j] = gW2[((size_t)t * HDIM + k) * HDIM + j];
  __syncthreads();
  float acc = 0.f;
#pragma unroll 8
  for (int c = 0; c < HDIM; ++c) acc += row[c] * Wx[c * H3 + j];
  Wf[((size_t)t * HDIM + k) * H3 + j] = acc;
}

__global__ __launch_bounds__(384) void fuse_b(
    const float* __restrict__ gb2, const float* __restrict__ Wx,
    const float* __restrict__ bx, float* __restrict__ bf) {
  int t = blockIdx.x;
  int j = threadIdx.x;
  __shared__ float row[HDIM];
  if (j < HDIM) row[j] = gb2[t * HDIM + j];
  __syncthreads();
  float acc = bx[j];
#pragma unroll 8
  for (int c = 0; c < HDIM; ++c) acc += row[c] * Wx[c * H3 + j];
  bf[t * H3 + j] = acc;
}

// pack combined fp16 weights in MFMA-lane-coalesced layout:
// Bp[t][ks(8)][cg(32)][lr(4)][lj(16)] of v8h, where col = cg*16+lj, k = ks*32 + lr*8 + i.
__global__ __launch_bounds__(256) void pack_wcomb(
    const float* __restrict__ Wf32, const float* __restrict__ Wh,
    _Float16* __restrict__ Bp) {
  int t = blockIdx.x >> 9;
  int col = blockIdx.x & 511;
  int k = threadIdx.x;  // 0..255
  float v;
  if (col < 384) {
    if (k < 128) v = Wf32[((size_t)t * HDIM + k) * H3 + col];
    else v = (col < 256) ? Wh[(size_t)(k - 128) * H3 + col] : 0.f;
  } else {
    v = (k < 128) ? 0.f : Wh[(size_t)(k - 128) * H3 + (col - 128)];
  }
  int cg = col >> 4, lj = col & 15;
  int ks = k >> 5, rem = k & 31, lr = rem >> 3, ki = rem & 7;
  size_t idx = ((((((size_t)t * 8 + ks) * 32 + cg) * 4 + lr) * 16 + lj) * 8) + ki;
  Bp[idx] = (_Float16)v;
}

__global__ __launch_bounds__(512) void pack_bcomb(
    const float* __restrict__ bfb, const float* __restrict__ bh,
    float* __restrict__ bcomb) {
  int t = blockIdx.x;
  int c = threadIdx.x;
  float v;
  if (c < 256) v = bfb[t * H3 + c] + bh[c];
  else if (c < 384) v = bfb[t * H3 + c];
  else v = bh[c - 128];
  bcomb[t * 512 + c] = v;
}

// static encoder + attn init: acch (fp16) = se, sden = 1, mxv = logit
__global__ __launch_bounds__(128) void static_encode_attn_init(
    const float* __restrict__ dense, const int* __restrict__ sparse,
    const float* __restrict__ emb,
    const float* __restrict__ Ws, const float* __restrict__ bs,
    const float* __restrict__ Waw, const float* __restrict__ baw,
    _Float16* __restrict__ acch, float* __restrict__ s, float* __restrict__ mx) {
  int n = blockIdx.x;
  int j = threadIdx.x;
  __shared__ float xs[G0DIM];
  if (j < G0DIM) {
    float v;
    if (j < 16) {
      v = emb[sparse[n * 2 + 0] * 16 + j];
    } else if (j < 32) {
      v = emb[VVOCAB * 16 + sparse[n * 2 + 1] * 16 + (j - 16)];
    } else {
      v = dense[n * DDIM + (j - 32)];
    }
    xs[j] = v;
  }
  __syncthreads();
  float a = bs[j];
#pragma unroll 16
  for (int k = 0; k < G0DIM; ++k) a += xs[k] * Ws[k * HDIM + j];
  a = fmaxf(a, 0.f);
  float v = tanhf(a) * Waw[j];
  __shared__ float red[2];
  int lane = j & 63, wid = j >> 6;
#pragma unroll
  for (int off = 32; off > 0; off >>= 1) v += __shfl_down(v, off, 64);
  if (lane == 0) red[wid] = v;
  __syncthreads();
  acch[(size_t)n * HDIM + j] = (_Float16)a;
  if (j == 0) {
    s[n] = 1.f;
    mx[n] = red[0] + red[1] + baw[0];
  }
}

__global__ __launch_bounds__(256) void dynx_gather_h(
    const float* __restrict__ dense_t, const int* __restrict__ sparse_t,
    const float* __restrict__ emb, _Float16* __restrict__ xout) {
  int idx = blockIdx.x * 256 + threadIdx.x;  // over N*8
  int n = idx >> 3, k8 = idx & 7;
  if (n >= NNODES) return;
  const float* src;
  if (k8 < 2)
    src = &emb[sparse_t[n * 2 + 0] * 16 + k8 * 8];
  else if (k8 < 4)
    src = &emb[VVOCAB * 16 + sparse_t[n * 2 + 1] * 16 + (k8 - 2) * 8];
  else
    src = &dense_t[n * DDIM + (k8 - 4) * 8];
  float4 f0 = *(const float4*)src;
  float4 f1 = *(const float4*)(src + 4);
  v8h v = {(_Float16)f0.x, (_Float16)f0.y, (_Float16)f0.z, (_Float16)f0.w,
           (_Float16)f1.x, (_Float16)f1.y, (_Float16)f1.z, (_Float16)f1.w};
  *(v8h*)&xout[(size_t)n * G0DIM + k8 * 8] = v;
}

__global__ __launch_bounds__(64) void rowmm64(
    const _Float16* __restrict__ x, const float* __restrict__ W,
    const float* __restrict__ b, _Float16* __restrict__ y) {
  const int NB = 8;
  int n0 = blockIdx.x * NB;
  int j = threadIdx.x;
  __shared__ float xT[G0DIM][12];
#pragma unroll
  for (int q = 0; q < NB; ++q) xT[j][q] = (float)x[(size_t)(n0 + q) * G0DIM + j];
  __syncthreads();
  float acc0[NB], acc1[NB];
#pragma unroll
  for (int q = 0; q < NB; ++q) { acc0[q] = 0.f; acc1[q] = 0.f; }
#pragma unroll 4
  for (int k = 0; k < G0DIM; ++k) {
    float4 a = *(const float4*)&xT[k][0];
    float4 c = *(const float4*)&xT[k][4];
    float w0 = W[(size_t)k * HDIM + j];
    float w1 = W[(size_t)k * HDIM + j + 64];
    acc0[0] += a.x * w0; acc0[1] += a.y * w0; acc0[2] += a.z * w0; acc0[3] += a.w * w0;
    acc0[4] += c.x * w0; acc0[5] += c.y * w0; acc0[6] += c.z * w0; acc0[7] += c.w * w0;
    acc1[0] += a.x * w1; acc1[1] += a.y * w1; acc1[2] += a.z * w1; acc1[3] += a.w * w1;
    acc1[4] += c.x * w1; acc1[5] += c.y * w1; acc1[6] += c.z * w1; acc1[7] += c.w * w1;
  }
  float b0 = b[j], b1 = b[j + 64];
#pragma unroll
  for (int q = 0; q < NB; ++q) {
    y[(size_t)(n0 + q) * HDIM + j] = (_Float16)fmaxf(acc0[q] + b0, 0.f);
    y[(size_t)(n0 + q) * HDIM + j + 64] = (_Float16)fmaxf(acc1[q] + b1, 0.f);
  }
}

__device__ __forceinline__ float sigmoidf_(float v) {
  return 1.f / (1.f + expf(-v));
}

// MFMA GRU + attention. Coalesced B layout; fp16 h_lds.
__global__ __launch_bounds__(256) void gru_mfma(
    const _Float16* __restrict__ Xh, const _Float16* __restrict__ Hp,
    const _Float16* __restrict__ Bt, const float* __restrict__ bcomb,
    const float* __restrict__ Waw, const float* __restrict__ baw,
    _Float16* __restrict__ hout, _Float16* __restrict__ acch,
    float* __restrict__ outf, float* __restrict__ sden, float* __restrict__ mxv,
    int last) {
  const int AST = 264;
  __shared__ _Float16 A_lds[32 * AST];
  __shared__ _Float16 h_lds[32 * 132];
  __shared__ float lg[32], facs[32], ps[32], sdn[32];
  int tid = threadIdx.x;
  int w = tid >> 6, lane = tid & 63;
  int n0 = blockIdx.x * 32;

#pragma unroll
  for (int i = 0; i < 4; ++i) {
    int cid = tid + i * 256;
    int row = cid >> 5, ch = cid & 31;
    int n = n0 + row;
    v8h v = {(_Float16)0, (_Float16)0, (_Float16)0, (_Float16)0,
             (_Float16)0, (_Float16)0, (_Float16)0, (_Float16)0};
    if (n < NNODES) {
      if (ch < 16) v = *(const v8h*)&Xh[(size_t)n * HDIM + ch * 8];
      else if (Hp) v = *(const v8h*)&Hp[(size_t)n * HDIM + (ch - 16) * 8];
    }
    *(v8h*)&A_lds[row * AST + ch * 8] = v;
  }
  __syncthreads();

  int lj = lane & 15, lr = lane >> 4;
  const v8h* Bp = (const v8h*)Bt;  // [ks][cg][lr][lj] fragments, lane-coalesced
  v4f accf[2][8];
#pragma unroll
  for (int m = 0; m < 2; ++m)
#pragma unroll
    for (int f = 0; f < 8; ++f) accf[m][f] = (v4f){0.f, 0.f, 0.f, 0.f};

  for (int ks = 0; ks < 8; ++ks) {
    v8h a0 = *(const v8h*)&A_lds[lj * AST + ks * 32 + lr * 8];
    v8h a1 = *(const v8h*)&A_lds[(16 + lj) * AST + ks * 32 + lr * 8];
#pragma unroll
    for (int g = 0; g < 4; ++g)
#pragma unroll
      for (int p = 0; p < 2; ++p) {
        int cg = g * 8 + w * 2 + p;
        v8h b = Bp[((ks * 32 + cg) * 4 + lr) * 16 + lj];
        accf[0][g * 2 + p] =
            __builtin_amdgcn_mfma_f32_16x16x32_f16(a0, b, accf[0][g * 2 + p], 0, 0, 0);
        accf[1][g * 2 + p] =
            __builtin_amdgcn_mfma_f32_16x16x32_f16(a1, b, accf[1][g * 2 + p], 0, 0, 0);
      }
  }

#pragma unroll
  for (int p = 0; p < 2; ++p) {
    int j = (w * 2 + p) * 16 + lj;
    float br = bcomb[j], bz = bcomb[128 + j], bxn = bcomb[256 + j], bhn = bcomb[384 + j];
#pragma unroll
    for (int m = 0; m < 2; ++m)
#pragma unroll
      for (int reg = 0; reg < 4; ++reg) {
        int row = m * 16 + lr * 4 + reg;
        float r = sigmoidf_(accf[m][0 + p][reg] + br);
        float z = sigmoidf_(accf[m][2 + p][reg] + bz);
        float hp = (float)A_lds[row * AST + 128 + j];
        float nc = tanhf(accf[m][4 + p][reg] + bxn + r * (accf[m][6 + p][reg] + bhn));
        h_lds[row * 132 + j] = (_Float16)((1.f - z) * nc + z * hp);
      }
  }
  __syncthreads();

  float waw0 = Waw[lane], waw1 = Waw[lane + 64];
#pragma unroll
  for (int q = 0; q < 8; ++q) {
    int row = w * 8 + q;
    float v = tanhf((float)h_lds[row * 132 + lane]) * waw0 +
              tanhf((float)h_lds[row * 132 + lane + 64]) * waw1;
#pragma unroll
    for (int off = 32; off > 0; off >>= 1) v += __shfl_down(v, off, 64);
    if (lane == 0) lg[row] = v;
  }
  __syncthreads();
  if (tid < 32) {
    int n = n0 + tid;
    if (n < NNODES) {
      float l = lg[tid] + baw[0];
      float m = mxv[n];
      float mnew = fmaxf(m, l);
      float fac = expf(m - mnew);
      float pp = expf(l - mnew);
      facs[tid] = fac;
      ps[tid] = pp;
      float snew = sden[n] * fac + pp;
      sdn[tid] = snew;
      sden[n] = snew;
      mxv[n] = mnew;
    }
  }
  __syncthreads();
  if (last) {
#pragma unroll
    for (int i = 0; i < 16; ++i) {
      int idx = tid + i * 256;
      int row = idx >> 7, col = idx & 127;
      int n = n0 + row;
      if (n < NNODES) {
        float hv = (float)h_lds[row * 132 + col];
        size_t o = (size_t)n * HDIM + col;
        float av = (float)acch[o];
        outf[o] = (av * facs[row] + ps[row] * hv) / sdn[row];
      }
    }
  } else {
#pragma unroll
    for (int i = 0; i < 16; ++i) {
      int idx = tid + i * 256;
      int row = idx >> 7, col = idx & 127;
      int n = n0 + row;
      if (n < NNODES) {
        float hv = (float)h_lds[row * 132 + col];
        size_t o = (size_t)n * HDIM + col;
        float av = (float)acch[o];
        acch[o] = (_Float16)(av * facs[row] + ps[row] * hv);
        hout[o] = (_Float16)hv;
      }
    }
  }
}

extern "C" void kernel_launch(void* const* d_in, const int* in_sizes, int n_in,
                              void* d_out, int out_size, void* d_ws, size_t ws_size,
                              hipStream_t stream) {
  const float* static_dense = (const float*)d_in[0];
  const int*   static_sparse = (const int*)d_in[1];
  const float* dyn_dense = (const float*)d_in[2];
  const int*   dyn_sparse = (const int*)d_in[3];
  const int*   edges = (const int*)d_in[4];
  const float* weights = (const float*)d_in[5];
  const float* s_emb = (const float*)d_in[6];
  const float* d_emb = (const float*)d_in[7];
  const float* Ws = (const float*)d_in[8];
  const float* bs = (const float*)d_in[9];
  const float* gW1 = (const float*)d_in[10];
  const float* gb1 = (const float*)d_in[11];
  const float* gW2 = (const float*)d_in[12];
  const float* gb2 = (const float*)d_in[13];
  const float* Wx = (const float*)d_in[14];
  const float* Wh = (const float*)d_in[15];
  const float* bx = (const float*)d_in[16];
  const float* bh_in = (const float*)d_in[17];
  const float* Waw = (const float*)d_in[18];
  const float* baw = (const float*)d_in[19];
  float* out = (float*)d_out;  // final fp32 output [N,128], written by last gru_mfma

  const size_t N = NNODES;
  char* p = (char*)d_ws;
  auto alloc = [&](size_t bytes) { char* r = p; p += (bytes + 255) & ~(size_t)255; return r; };
  float*     sden   = (float*)alloc(N * 4);
  float*     mxv    = (float*)alloc(N * 4);
  _Float16*  acch   = (_Float16*)alloc(N * HDIM * 2);      // fp16 attention accumulator
  // Big block: loop buffers; tmp (51.2MB) aliases it — tmp is fully consumed by fine_sort
  // BEFORE the loop's first write into any of these (stream order).
  char*      big    = alloc(64UL * 1024 * 1024);
  _Float16*  hA     = (_Float16*)big;                      // 12.8MB
  _Float16*  hB     = hA + N * HDIM;                       // 12.8MB
  _Float16*  dynx   = hB + N * HDIM;                       // 6.4MB
  _Float16*  m1h    = dynx + N * G0DIM;                    // 6.4MB
  _Float16*  h1h    = m1h + N * G0DIM;                     // 12.8MB
  _Float16*  Xh     = h1h + N * HDIM;                      // 12.8MB
  int2*      tmp    = (int2*)big;                          // 51.2MB alias
  float*     Wf32   = (float*)alloc((size_t)TSTEPS * HDIM * H3 * 4);
  _Float16*  Wcombt = (_Float16*)alloc((size_t)TSTEPS * 512 * 256 * 2);
  float*     bfb    = (float*)alloc((size_t)TSTEPS * H3 * 4);
  float*     bcomb  = (float*)alloc((size_t)TSTEPS * 512 * 4);
  int*       bhist  = (int*)alloc((size_t)TSTEPS * NSCN * 4);
  int*       bscan  = (int*)alloc((size_t)TSTEPS * NSCN * 4);
  int*       blofs  = (int*)alloc((size_t)TSTEPS * NBLK * COARSE * 4);  // 0.8MB
  int*       csum   = (int*)alloc((size_t)TSTEPS * NCHK2 * 4);
  int*       cbase  = (int*)alloc((size_t)TSTEPS * NCHK2 * 4);
  int*       offs   = (int*)alloc((size_t)TSTEPS * (NKEY + 1) * 4);
  unsigned int* csr = (unsigned int*)alloc((size_t)TSTEPS * NEDGES * 4);  // 25.6MB packed

  // ---- atomic-free two-level counting sort (all timesteps) ----
  coarse_hist<<<dim3(NBLK, TSTEPS), 512, 0, stream>>>(edges, bhist, blofs);
  scan_c1<<<TSTEPS * NCHK2, 256, 0, stream>>>(bhist, csum);
  scan_c2<<<TSTEPS, 512, 0, stream>>>(csum, cbase);
  scan_c3<<<TSTEPS * NCHK2, 512, 0, stream>>>(bhist, cbase, bscan);
  coarse_scatter<<<dim3(NBLK, TSTEPS), 512, 0, stream>>>(edges, weights, blofs, tmp);
  fine_sort<<<dim3(COARSE, TSTEPS), 512, 0, stream>>>(bscan, bhist, blofs, tmp, csr, offs);

  // ---- weight/bias preprocessing ----
  fuse_w<<<TSTEPS * HDIM, H3, 0, stream>>>(gW2, Wx, Wf32);
  fuse_b<<<TSTEPS, H3, 0, stream>>>(gb2, Wx, bx, bfb);
  pack_wcomb<<<TSTEPS * 512, 256, 0, stream>>>(Wf32, Wh, Wcombt);
  pack_bcomb<<<TSTEPS, 512, 0, stream>>>(bfb, bh_in, bcomb);

  static_encode_attn_init<<<NNODES, 128, 0, stream>>>(
      static_dense, static_sparse, s_emb, Ws, bs, Waw, baw, acch, sden, mxv);

  const int GRUB = (NNODES + 31) / 32;
  for (int t = 0; t < TSTEPS; ++t) {
    const int* off_t = offs + (size_t)t * (NKEY + 1);
    const unsigned int* csr_t = csr + (size_t)t * NEDGES;
    _Float16* hcur = (t & 1) ? hB : hA;
    const _Float16* hprev = (t == 0) ? nullptr : ((t & 1) ? hA : hB);

    dynx_gather_h<<<(NNODES * 8 + 255) / 256, 256, 0, stream>>>(
        dyn_dense + (size_t)t * N * DDIM, dyn_sparse + (size_t)t * N * 2, d_emb, dynx);

    gather_merged<G0DIM><<<(NNODES + 31) / 32, 256, 0, stream>>>(off_t, csr_t, dynx, m1h);

    rowmm64<<<NNODES / 8, 64, 0, stream>>>(
        m1h, gW1 + (size_t)t * G0DIM * HDIM, gb1 + (size_t)t * HDIM, h1h);

    gather_merged<HDIM><<<(NNODES + 15) / 16, 256, 0, stream>>>(off_t, csr_t, h1h, Xh);

    gru_mfma<<<GRUB, 256, 0, stream>>>(
        Xh, hprev, Wcombt + (size_t)t * 512 * 256, bcomb + t * 512,
        Waw, baw, hcur, acch, out, sden, mxv, t == TSTEPS - 1 ? 1 : 0);
  }
}

// Round 22
// 1206.023 us; speedup vs baseline: 1.0650x; 1.0650x over previous
//
#include <hip/hip_runtime.h>
#include <hip/hip_bf16.h>
#include <string.h>

#define NNODES 50000
#define TSTEPS 8
#define NEDGES 800000
#define VVOCAB 1000
#define DDIM 32
#define HDIM 128
#define G0DIM 64
#define H3 384
#define NSB 4          // src blocks: key = dst*NSB + src/SRCBLK
#define SRCBLK 12500
#define NKEY (NNODES * NSB)      // 200000 keys per timestep
#define NBLK 128                 // edge blocks per timestep for the sort
#define EPB 6250                 // edges per block (128*6250 = 800000 exactly)
#define COARSE 391               // coarse bins = key>>9 (max key 199999 -> 390)
#define FINEN 512                // fine keys per coarse bin (key & 511)
#define NSCN (COARSE * NBLK)     // 50048
#define NCHK2 98                 // ceil(NSCN/512)
#define STAGE_CAP 4096           // LDS staging capacity for fine_sort bins

typedef _Float16 v8h __attribute__((ext_vector_type(8)));
typedef float v4f __attribute__((ext_vector_type(4)));

__device__ __forceinline__ float w_decode(unsigned int packed) {
  unsigned short wb = (unsigned short)(packed >> 16);
  _Float16 h;
  __builtin_memcpy(&h, &wb, 2);
  return (float)h;
}

// ============== Atomic-free two-level counting sort (CSR build) ===========================

// A1: per-block LDS histogram over coarse bins -> bh[t][coarse*NBLK + block]
__global__ __launch_bounds__(512) void coarse_hist(const int* __restrict__ edges,
                                                   int* __restrict__ bh) {
  __shared__ int hist[COARSE];
  int t = blockIdx.y, b = blockIdx.x, tid = threadIdx.x;
  for (int i = tid; i < COARSE; i += 512) hist[i] = 0;
  __syncthreads();
  const int* srcp = edges + (size_t)t * 2 * NEDGES + (size_t)b * EPB;
  const int* dstp = srcp + NEDGES;
  for (int i = tid; i < EPB; i += 512) {
    int key = dstp[i] * NSB + srcp[i] / SRCBLK;
    atomicAdd(&hist[key >> 9], 1);
  }
  __syncthreads();
  for (int i = tid; i < COARSE; i += 512) bh[(size_t)t * NSCN + i * NBLK + b] = hist[i];
}

// scan of bh[t][0..NSCN) -> bscan (exclusive), hierarchical
__global__ __launch_bounds__(256) void scan_c1(const int* __restrict__ bh,
                                               int* __restrict__ csum) {
  int bid = blockIdx.x;  // t*NCHK2 + c
  int t = bid / NCHK2, c = bid % NCHK2;
  int tid = threadIdx.x;
  int s = 0;
#pragma unroll
  for (int i = 0; i < 2; ++i) {
    int n = c * 512 + tid + i * 256;
    if (n < NSCN) s += bh[(size_t)t * NSCN + n];
  }
#pragma unroll
  for (int off = 32; off > 0; off >>= 1) s += __shfl_down(s, off, 64);
  __shared__ int wsum[4];
  if ((tid & 63) == 0) wsum[tid >> 6] = s;
  __syncthreads();
  if (tid == 0) csum[bid] = wsum[0] + wsum[1] + wsum[2] + wsum[3];
}

__global__ __launch_bounds__(512) void scan_c2(const int* __restrict__ csum,
                                               int* __restrict__ cbase) {
  int t = blockIdx.x;
  int tid = threadIdx.x;
  __shared__ int buf[512];
  int own = (tid < NCHK2) ? csum[t * NCHK2 + tid] : 0;
  buf[tid] = own;
  __syncthreads();
  for (int d = 1; d < 512; d <<= 1) {
    int v = (tid >= d) ? buf[tid - d] : 0;
    __syncthreads();
    buf[tid] += v;
    __syncthreads();
  }
  if (tid < NCHK2) cbase[t * NCHK2 + tid] = buf[tid] - own;
}

__global__ __launch_bounds__(512) void scan_c3(const int* __restrict__ bh,
                                               const int* __restrict__ cbase,
                                               int* __restrict__ bscan) {
  int bid = blockIdx.x;
  int t = bid / NCHK2, c = bid % NCHK2;
  int tid = threadIdx.x;
  int n = c * 512 + tid;
  int d = (n < NSCN) ? bh[(size_t)t * NSCN + n] : 0;
  __shared__ int buf[512];
  buf[tid] = d;
  __syncthreads();
  for (int s = 1; s < 512; s <<= 1) {
    int v = (tid >= s) ? buf[tid - s] : 0;
    __syncthreads();
    buf[tid] += v;
    __syncthreads();
  }
  if (n < NSCN) bscan[(size_t)t * NSCN + n] = cbase[bid] + buf[tid] - d;
}

// A3: LDS-staged scatter. Block sorts its 6250 edges by coarse bin in LDS, then sweeps
// out linearly: consecutive elements -> consecutive global addresses within bin runs.
__global__ __launch_bounds__(512) void coarse_scatter(
    const int* __restrict__ edges, const float* __restrict__ weights,
    const int* __restrict__ bscan, int2* __restrict__ tmp) {
  __shared__ int hist[COARSE], lstart[COARSE], cur[COARSE], scanb[COARSE];
  __shared__ int2 stage[EPB];  // 50KB
  int t = blockIdx.y, b = blockIdx.x, tid = threadIdx.x;
  for (int i = tid; i < COARSE; i += 512) hist[i] = 0;
  __syncthreads();
  const int* srcp = edges + (size_t)t * 2 * NEDGES + (size_t)b * EPB;
  const int* dstp = srcp + NEDGES;
  const float* wp = weights + (size_t)t * NEDGES + (size_t)b * EPB;
  // pass 1: keys + histogram (keys recomputed in pass 2; edges are L2-hot)
  for (int i = tid; i < EPB; i += 512) {
    int key = dstp[i] * NSB + srcp[i] / SRCBLK;
    atomicAdd(&hist[key >> 9], 1);
  }
  __syncthreads();
  // LDS exclusive scan over COARSE
  if (tid < COARSE) scanb[tid] = hist[tid];
  __syncthreads();
  for (int d = 1; d < COARSE; d <<= 1) {
    int v = 0;
    if (tid < COARSE && tid >= d) v = scanb[tid - d];
    __syncthreads();
    if (tid < COARSE) scanb[tid] += v;
    __syncthreads();
  }
  if (tid < COARSE) {
    int ls = scanb[tid] - hist[tid];
    lstart[tid] = ls;
    cur[tid] = ls;
  }
  __syncthreads();
  // pass 2: scatter into LDS stage (bin-sorted)
  for (int i = tid; i < EPB; i += 512) {
    int src = srcp[i];
    int key = dstp[i] * NSB + src / SRCBLK;
    int coarse = key >> 9, fine = key & 511;
    int lpos = atomicAdd(&cur[coarse], 1);  // LDS atomic
    int2 pk;
    pk.x = src | (fine << 16);
    pk.y = __float_as_int(wp[i]);
    stage[lpos] = pk;
  }
  __syncthreads();
  // sweep-out: binary search bin of j, write to global bin-major position
  for (int j = tid; j < EPB; j += 512) {
    int lo = 0, hi = COARSE - 1;
    while (lo < hi) {
      int mid = (lo + hi + 1) >> 1;
      if (lstart[mid] <= j) lo = mid;
      else hi = mid - 1;
    }
    int gpos = bscan[(size_t)t * NSCN + lo * NBLK + b] + (j - lstart[lo]);
    tmp[(size_t)t * NEDGES + gpos] = stage[j];
  }
}

// B: per (t,coarse) bin: LDS counting sort over 512 fine keys -> packed 4B csr + offs.
__global__ __launch_bounds__(512) void fine_sort(
    const int* __restrict__ bscan, const int2* __restrict__ tmp,
    unsigned int* __restrict__ csr, int* __restrict__ offs) {
  __shared__ int fhist[FINEN], fbase[FINEN], fcur[FINEN], buf[FINEN];
  __shared__ unsigned int stage[STAGE_CAP];
  int t = blockIdx.y, coarse = blockIdx.x, tid = threadIdx.x;
  int cb0 = bscan[(size_t)t * NSCN + coarse * NBLK];
  int cb1 = (coarse == COARSE - 1) ? NEDGES : bscan[(size_t)t * NSCN + (coarse + 1) * NBLK];
  int size = cb1 - cb0;
  fhist[tid] = 0;
  fcur[tid] = 0;
  __syncthreads();
  const int2* bin = tmp + (size_t)t * NEDGES + cb0;
  for (int i = tid; i < size; i += 512) {
    int fine = (bin[i].x >> 16) & 511;
    atomicAdd(&fhist[fine], 1);
  }
  __syncthreads();
  buf[tid] = fhist[tid];
  __syncthreads();
  for (int d = 1; d < FINEN; d <<= 1) {
    int v = (tid >= d) ? buf[tid - d] : 0;
    __syncthreads();
    buf[tid] += v;
    __syncthreads();
  }
  fbase[tid] = buf[tid] - fhist[tid];
  int key = coarse * FINEN + tid;
  if (key < NKEY) offs[(size_t)t * (NKEY + 1) + key] = cb0 + fbase[tid];
  if (coarse == COARSE - 1 && tid == 0) offs[(size_t)t * (NKEY + 1) + NKEY] = NEDGES;
  __syncthreads();
  unsigned int* outp = csr + (size_t)t * NEDGES + cb0;
  if (size <= STAGE_CAP) {
    for (int i = tid; i < size; i += 512) {
      int2 p = bin[i];
      int fine = (p.x >> 16) & 511;
      int lr = atomicAdd(&fcur[fine], 1);  // LDS atomic
      _Float16 wh = (_Float16)__int_as_float(p.y);
      unsigned short wb;
      __builtin_memcpy(&wb, &wh, 2);
      stage[fbase[fine] + lr] = (unsigned int)(p.x & 0xFFFF) | ((unsigned int)wb << 16);
    }
    __syncthreads();
    for (int i = tid; i < size; i += 512) outp[i] = stage[i];
  } else {
    for (int i = tid; i < size; i += 512) {
      int2 p = bin[i];
      int fine = (p.x >> 16) & 511;
      int lr = atomicAdd(&fcur[fine], 1);  // LDS atomic
      _Float16 wh = (_Float16)__int_as_float(p.y);
      unsigned short wb;
      __builtin_memcpy(&wb, &wh, 2);
      outp[fbase[fine] + lr] = (unsigned int)(p.x & 0xFFFF) | ((unsigned int)wb << 16);
    }
  }
}

// ============== Gathers (4B packed csr entries) ===========================================

template <int D>
__global__ __launch_bounds__(256) void gather_merged(
    const int* __restrict__ off, const unsigned int* __restrict__ csr,
    const _Float16* __restrict__ x, _Float16* __restrict__ m) {
  const int LPN = D / 8;
  int n = blockIdx.x * (256 / LPN) + threadIdx.x / LPN;
  int l = threadIdx.x % LPN;
  if (n >= NNODES) return;
  int s0 = off[n * NSB], s1 = off[(n + 1) * NSB];
  float a0[8], a1[8];
#pragma unroll
  for (int i = 0; i < 8; ++i) { a0[i] = 0.f; a1[i] = 0.f; }
  int e = s0;
  for (; e + 1 < s1; e += 2) {
    unsigned int eA = csr[e], eB = csr[e + 1];
    v8h xA = *(const v8h*)&x[(size_t)(eA & 0xFFFF) * D + l * 8];
    v8h xB = *(const v8h*)&x[(size_t)(eB & 0xFFFF) * D + l * 8];
    float wA = w_decode(eA), wB = w_decode(eB);
#pragma unroll
    for (int i = 0; i < 8; ++i) {
      a0[i] += wA * (float)xA[i];
      a1[i] += wB * (float)xB[i];
    }
  }
  if (e < s1) {
    unsigned int eA = csr[e];
    v8h xA = *(const v8h*)&x[(size_t)(eA & 0xFFFF) * D + l * 8];
    float wA = w_decode(eA);
#pragma unroll
    for (int i = 0; i < 8; ++i) a0[i] += wA * (float)xA[i];
  }
  v8h r;
#pragma unroll
  for (int i = 0; i < 8; ++i) r[i] = (_Float16)(a0[i] + a1[i]);
  *(v8h*)&m[(size_t)n * D + l * 8] = r;
}

// ============== Dense kernels =============================================================

__global__ __launch_bounds__(384) void fuse_w(
    const float* __restrict__ gW2, const float* __restrict__ Wx, float* __restrict__ Wf) {
  int t = blockIdx.x >> 7;
  int k = blockIdx.x & 127;
  int j = threadIdx.x;
  __shared__ float row[HDIM];
  if (j < HDIM) row[j] = gW2[((size_t)t * HDIM + k) * HDIM + j];
  __syncthreads();
  float acc = 0.f;
#pragma unroll 8
  for (int c = 0; c < HDIM; ++c) acc += row[c] * Wx[c * H3 + j];
  Wf[((size_t)t * HDIM + k) * H3 + j] = acc;
}

__global__ __launch_bounds__(384) void fuse_b(
    const float* __restrict__ gb2, const float* __restrict__ Wx,
    const float* __restrict__ bx, float* __restrict__ bf) {
  int t = blockIdx.x;
  int j = threadIdx.x;
  __shared__ float row[HDIM];
  if (j < HDIM) row[j] = gb2[t * HDIM + j];
  __syncthreads();
  float acc = bx[j];
#pragma unroll 8
  for (int c = 0; c < HDIM; ++c) acc += row[c] * Wx[c * H3 + j];
  bf[t * H3 + j] = acc;
}

// pack combined fp16 weights in MFMA-lane-coalesced layout:
// Bp[t][ks(8)][cg(32)][lr(4)][lj(16)] of v8h, where col = cg*16+lj, k = ks*32 + lr*8 + i.
__global__ __launch_bounds__(256) void pack_wcomb(
    const float* __restrict__ Wf32, const float* __restrict__ Wh,
    _Float16* __restrict__ Bp) {
  int t = blockIdx.x >> 9;
  int col = blockIdx.x & 511;
  int k = threadIdx.x;  // 0..255
  float v;
  if (col < 384) {
    if (k < 128) v = Wf32[((size_t)t * HDIM + k) * H3 + col];
    else v = (col < 256) ? Wh[(size_t)(k - 128) * H3 + col] : 0.f;
  } else {
    v = (k < 128) ? 0.f : Wh[(size_t)(k - 128) * H3 + (col - 128)];
  }
  int cg = col >> 4, lj = col & 15;
  int ks = k >> 5, rem = k & 31, lr = rem >> 3, ki = rem & 7;
  size_t idx = ((((((size_t)t * 8 + ks) * 32 + cg) * 4 + lr) * 16 + lj) * 8) + ki;
  Bp[idx] = (_Float16)v;
}

__global__ __launch_bounds__(512) void pack_bcomb(
    const float* __restrict__ bfb, const float* __restrict__ bh,
    float* __restrict__ bcomb) {
  int t = blockIdx.x;
  int c = threadIdx.x;
  float v;
  if (c < 256) v = bfb[t * H3 + c] + bh[c];
  else if (c < 384) v = bfb[t * H3 + c];
  else v = bh[c - 128];
  bcomb[t * 512 + c] = v;
}

// static encoder + attn init: acch (fp16) = se, sden = 1, mxv = logit
__global__ __launch_bounds__(128) void static_encode_attn_init(
    const float* __restrict__ dense, const int* __restrict__ sparse,
    const float* __restrict__ emb,
    const float* __restrict__ Ws, const float* __restrict__ bs,
    const float* __restrict__ Waw, const float* __restrict__ baw,
    _Float16* __restrict__ acch, float* __restrict__ s, float* __restrict__ mx) {
  int n = blockIdx.x;
  int j = threadIdx.x;
  __shared__ float xs[G0DIM];
  if (j < G0DIM) {
    float v;
    if (j < 16) {
      v = emb[sparse[n * 2 + 0] * 16 + j];
    } else if (j < 32) {
      v = emb[VVOCAB * 16 + sparse[n * 2 + 1] * 16 + (j - 16)];
    } else {
      v = dense[n * DDIM + (j - 32)];
    }
    xs[j] = v;
  }
  __syncthreads();
  float a = bs[j];
#pragma unroll 16
  for (int k = 0; k < G0DIM; ++k) a += xs[k] * Ws[k * HDIM + j];
  a = fmaxf(a, 0.f);
  float v = tanhf(a) * Waw[j];
  __shared__ float red[2];
  int lane = j & 63, wid = j >> 6;
#pragma unroll
  for (int off = 32; off > 0; off >>= 1) v += __shfl_down(v, off, 64);
  if (lane == 0) red[wid] = v;
  __syncthreads();
  acch[(size_t)n * HDIM + j] = (_Float16)a;
  if (j == 0) {
    s[n] = 1.f;
    mx[n] = red[0] + red[1] + baw[0];
  }
}

__global__ __launch_bounds__(256) void dynx_gather_h(
    const float* __restrict__ dense_t, const int* __restrict__ sparse_t,
    const float* __restrict__ emb, _Float16* __restrict__ xout) {
  int idx = blockIdx.x * 256 + threadIdx.x;  // over N*8
  int n = idx >> 3, k8 = idx & 7;
  if (n >= NNODES) return;
  const float* src;
  if (k8 < 2)
    src = &emb[sparse_t[n * 2 + 0] * 16 + k8 * 8];
  else if (k8 < 4)
    src = &emb[VVOCAB * 16 + sparse_t[n * 2 + 1] * 16 + (k8 - 2) * 8];
  else
    src = &dense_t[n * DDIM + (k8 - 4) * 8];
  float4 f0 = *(const float4*)src;
  float4 f1 = *(const float4*)(src + 4);
  v8h v = {(_Float16)f0.x, (_Float16)f0.y, (_Float16)f0.z, (_Float16)f0.w,
           (_Float16)f1.x, (_Float16)f1.y, (_Float16)f1.z, (_Float16)f1.w};
  *(v8h*)&xout[(size_t)n * G0DIM + k8 * 8] = v;
}

__global__ __launch_bounds__(64) void rowmm64(
    const _Float16* __restrict__ x, const float* __restrict__ W,
    const float* __restrict__ b, _Float16* __restrict__ y) {
  const int NB = 8;
  int n0 = blockIdx.x * NB;
  int j = threadIdx.x;
  __shared__ float xT[G0DIM][12];
#pragma unroll
  for (int q = 0; q < NB; ++q) xT[j][q] = (float)x[(size_t)(n0 + q) * G0DIM + j];
  __syncthreads();
  float acc0[NB], acc1[NB];
#pragma unroll
  for (int q = 0; q < NB; ++q) { acc0[q] = 0.f; acc1[q] = 0.f; }
#pragma unroll 4
  for (int k = 0; k < G0DIM; ++k) {
    float4 a = *(const float4*)&xT[k][0];
    float4 c = *(const float4*)&xT[k][4];
    float w0 = W[(size_t)k * HDIM + j];
    float w1 = W[(size_t)k * HDIM + j + 64];
    acc0[0] += a.x * w0; acc0[1] += a.y * w0; acc0[2] += a.z * w0; acc0[3] += a.w * w0;
    acc0[4] += c.x * w0; acc0[5] += c.y * w0; acc0[6] += c.z * w0; acc0[7] += c.w * w0;
    acc1[0] += a.x * w1; acc1[1] += a.y * w1; acc1[2] += a.z * w1; acc1[3] += a.w * w1;
    acc1[4] += c.x * w1; acc1[5] += c.y * w1; acc1[6] += c.z * w1; acc1[7] += c.w * w1;
  }
  float b0 = b[j], b1 = b[j + 64];
#pragma unroll
  for (int q = 0; q < NB; ++q) {
    y[(size_t)(n0 + q) * HDIM + j] = (_Float16)fmaxf(acc0[q] + b0, 0.f);
    y[(size_t)(n0 + q) * HDIM + j + 64] = (_Float16)fmaxf(acc1[q] + b1, 0.f);
  }
}

__device__ __forceinline__ float sigmoidf_(float v) {
  return 1.f / (1.f + expf(-v));
}

// MFMA GRU + attention. Coalesced B layout; fp16 h_lds.
__global__ __launch_bounds__(256) void gru_mfma(
    const _Float16* __restrict__ Xh, const _Float16* __restrict__ Hp,
    const _Float16* __restrict__ Bt, const float* __restrict__ bcomb,
    const float* __restrict__ Waw, const float* __restrict__ baw,
    _Float16* __restrict__ hout, _Float16* __restrict__ acch,
    float* __restrict__ outf, float* __restrict__ sden, float* __restrict__ mxv,
    int last) {
  const int AST = 264;
  __shared__ _Float16 A_lds[32 * AST];
  __shared__ _Float16 h_lds[32 * 132];
  __shared__ float lg[32], facs[32], ps[32], sdn[32];
  int tid = threadIdx.x;
  int w = tid >> 6, lane = tid & 63;
  int n0 = blockIdx.x * 32;

#pragma unroll
  for (int i = 0; i < 4; ++i) {
    int cid = tid + i * 256;
    int row = cid >> 5, ch = cid & 31;
    int n = n0 + row;
    v8h v = {(_Float16)0, (_Float16)0, (_Float16)0, (_Float16)0,
             (_Float16)0, (_Float16)0, (_Float16)0, (_Float16)0};
    if (n < NNODES) {
      if (ch < 16) v = *(const v8h*)&Xh[(size_t)n * HDIM + ch * 8];
      else if (Hp) v = *(const v8h*)&Hp[(size_t)n * HDIM + (ch - 16) * 8];
    }
    *(v8h*)&A_lds[row * AST + ch * 8] = v;
  }
  __syncthreads();

  int lj = lane & 15, lr = lane >> 4;
  const v8h* Bp = (const v8h*)Bt;  // [ks][cg][lr][lj] fragments, lane-coalesced
  v4f accf[2][8];
#pragma unroll
  for (int m = 0; m < 2; ++m)
#pragma unroll
    for (int f = 0; f < 8; ++f) accf[m][f] = (v4f){0.f, 0.f, 0.f, 0.f};

  for (int ks = 0; ks < 8; ++ks) {
    v8h a0 = *(const v8h*)&A_lds[lj * AST + ks * 32 + lr * 8];
    v8h a1 = *(const v8h*)&A_lds[(16 + lj) * AST + ks * 32 + lr * 8];
#pragma unroll
    for (int g = 0; g < 4; ++g)
#pragma unroll
      for (int p = 0; p < 2; ++p) {
        int cg = g * 8 + w * 2 + p;
        v8h b = Bp[((ks * 32 + cg) * 4 + lr) * 16 + lj];
        accf[0][g * 2 + p] =
            __builtin_amdgcn_mfma_f32_16x16x32_f16(a0, b, accf[0][g * 2 + p], 0, 0, 0);
        accf[1][g * 2 + p] =
            __builtin_amdgcn_mfma_f32_16x16x32_f16(a1, b, accf[1][g * 2 + p], 0, 0, 0);
      }
  }

#pragma unroll
  for (int p = 0; p < 2; ++p) {
    int j = (w * 2 + p) * 16 + lj;
    float br = bcomb[j], bz = bcomb[128 + j], bxn = bcomb[256 + j], bhn = bcomb[384 + j];
#pragma unroll
    for (int m = 0; m < 2; ++m)
#pragma unroll
      for (int reg = 0; reg < 4; ++reg) {
        int row = m * 16 + lr * 4 + reg;
        float r = sigmoidf_(accf[m][0 + p][reg] + br);
        float z = sigmoidf_(accf[m][2 + p][reg] + bz);
        float hp = (float)A_lds[row * AST + 128 + j];
        float nc = tanhf(accf[m][4 + p][reg] + bxn + r * (accf[m][6 + p][reg] + bhn));
        h_lds[row * 132 + j] = (_Float16)((1.f - z) * nc + z * hp);
      }
  }
  __syncthreads();

  float waw0 = Waw[lane], waw1 = Waw[lane + 64];
#pragma unroll
  for (int q = 0; q < 8; ++q) {
    int row = w * 8 + q;
    float v = tanhf((float)h_lds[row * 132 + lane]) * waw0 +
              tanhf((float)h_lds[row * 132 + lane + 64]) * waw1;
#pragma unroll
    for (int off = 32; off > 0; off >>= 1) v += __shfl_down(v, off, 64);
    if (lane == 0) lg[row] = v;
  }
  __syncthreads();
  if (tid < 32) {
    int n = n0 + tid;
    if (n < NNODES) {
      float l = lg[tid] + baw[0];
      float m = mxv[n];
      float mnew = fmaxf(m, l);
      float fac = expf(m - mnew);
      float pp = expf(l - mnew);
      facs[tid] = fac;
      ps[tid] = pp;
      float snew = sden[n] * fac + pp;
      sdn[tid] = snew;
      sden[n] = snew;
      mxv[n] = mnew;
    }
  }
  __syncthreads();
  if (last) {
#pragma unroll
    for (int i = 0; i < 16; ++i) {
      int idx = tid + i * 256;
      int row = idx >> 7, col = idx & 127;
      int n = n0 + row;
      if (n < NNODES) {
        float hv = (float)h_lds[row * 132 + col];
        size_t o = (size_t)n * HDIM + col;
        float av = (float)acch[o];
        outf[o] = (av * facs[row] + ps[row] * hv) / sdn[row];
      }
    }
  } else {
#pragma unroll
    for (int i = 0; i < 16; ++i) {
      int idx = tid + i * 256;
      int row = idx >> 7, col = idx & 127;
      int n = n0 + row;
      if (n < NNODES) {
        float hv = (float)h_lds[row * 132 + col];
        size_t o = (size_t)n * HDIM + col;
        float av = (float)acch[o];
        acch[o] = (_Float16)(av * facs[row] + ps[row] * hv);
        hout[o] = (_Float16)hv;
      }
    }
  }
}

extern "C" void kernel_launch(void* const* d_in, const int* in_sizes, int n_in,
                              void* d_out, int out_size, void* d_ws, size_t ws_size,
                              hipStream_t stream) {
  const float* static_dense = (const float*)d_in[0];
  const int*   static_sparse = (const int*)d_in[1];
  const float* dyn_dense = (const float*)d_in[2];
  const int*   dyn_sparse = (const int*)d_in[3];
  const int*   edges = (const int*)d_in[4];
  const float* weights = (const float*)d_in[5];
  const float* s_emb = (const float*)d_in[6];
  const float* d_emb = (const float*)d_in[7];
  const float* Ws = (const float*)d_in[8];
  const float* bs = (const float*)d_in[9];
  const float* gW1 = (const float*)d_in[10];
  const float* gb1 = (const float*)d_in[11];
  const float* gW2 = (const float*)d_in[12];
  const float* gb2 = (const float*)d_in[13];
  const float* Wx = (const float*)d_in[14];
  const float* Wh = (const float*)d_in[15];
  const float* bx = (const float*)d_in[16];
  const float* bh_in = (const float*)d_in[17];
  const float* Waw = (const float*)d_in[18];
  const float* baw = (const float*)d_in[19];
  float* out = (float*)d_out;  // final fp32 output [N,128], written by last gru_mfma

  const size_t N = NNODES;
  char* p = (char*)d_ws;
  auto alloc = [&](size_t bytes) { char* r = p; p += (bytes + 255) & ~(size_t)255; return r; };
  float*     sden   = (float*)alloc(N * 4);
  float*     mxv    = (float*)alloc(N * 4);
  _Float16*  acch   = (_Float16*)alloc(N * HDIM * 2);      // fp16 attention accumulator
  // Big block: loop buffers; tmp (51.2MB) aliases it — tmp is fully consumed by fine_sort
  // BEFORE the loop's first write into any of these (stream order).
  char*      big    = alloc(64UL * 1024 * 1024);
  _Float16*  hA     = (_Float16*)big;                      // 12.8MB
  _Float16*  hB     = hA + N * HDIM;                       // 12.8MB
  _Float16*  dynx   = hB + N * HDIM;                       // 6.4MB
  _Float16*  m1h    = dynx + N * G0DIM;                    // 6.4MB
  _Float16*  h1h    = m1h + N * G0DIM;                     // 12.8MB
  _Float16*  Xh     = h1h + N * HDIM;                      // 12.8MB
  int2*      tmp    = (int2*)big;                          // 51.2MB alias
  float*     Wf32   = (float*)alloc((size_t)TSTEPS * HDIM * H3 * 4);
  _Float16*  Wcombt = (_Float16*)alloc((size_t)TSTEPS * 512 * 256 * 2);
  float*     bfb    = (float*)alloc((size_t)TSTEPS * H3 * 4);
  float*     bcomb  = (float*)alloc((size_t)TSTEPS * 512 * 4);
  int*       bhist  = (int*)alloc((size_t)TSTEPS * NSCN * 4);   // 1.6MB
  int*       bscan  = (int*)alloc((size_t)TSTEPS * NSCN * 4);   // 1.6MB
  int*       csum   = (int*)alloc((size_t)TSTEPS * NCHK2 * 4);
  int*       cbase  = (int*)alloc((size_t)TSTEPS * NCHK2 * 4);
  int*       offs   = (int*)alloc((size_t)TSTEPS * (NKEY + 1) * 4);
  unsigned int* csr = (unsigned int*)alloc((size_t)TSTEPS * NEDGES * 4);  // 25.6MB packed

  // ---- atomic-free two-level counting sort (all timesteps) ----
  coarse_hist<<<dim3(NBLK, TSTEPS), 512, 0, stream>>>(edges, bhist);
  scan_c1<<<TSTEPS * NCHK2, 256, 0, stream>>>(bhist, csum);
  scan_c2<<<TSTEPS, 512, 0, stream>>>(csum, cbase);
  scan_c3<<<TSTEPS * NCHK2, 512, 0, stream>>>(bhist, cbase, bscan);
  coarse_scatter<<<dim3(NBLK, TSTEPS), 512, 0, stream>>>(edges, weights, bscan, tmp);
  fine_sort<<<dim3(COARSE, TSTEPS), 512, 0, stream>>>(bscan, tmp, csr, offs);

  // ---- weight/bias preprocessing ----
  fuse_w<<<TSTEPS * HDIM, H3, 0, stream>>>(gW2, Wx, Wf32);
  fuse_b<<<TSTEPS, H3, 0, stream>>>(gb2, Wx, bx, bfb);
  pack_wcomb<<<TSTEPS * 512, 256, 0, stream>>>(Wf32, Wh, Wcombt);
  pack_bcomb<<<TSTEPS, 512, 0, stream>>>(bfb, bh_in, bcomb);

  static_encode_attn_init<<<NNODES, 128, 0, stream>>>(
      static_dense, static_sparse, s_emb, Ws, bs, Waw, baw, acch, sden, mxv);

  const int GRUB = (NNODES + 31) / 32;
  for (int t = 0; t < TSTEPS; ++t) {
    const int* off_t = offs + (size_t)t * (NKEY + 1);
    const unsigned int* csr_t = csr + (size_t)t * NEDGES;
    _Float16* hcur = (t & 1) ? hB : hA;
    const _Float16* hprev = (t == 0) ? nullptr : ((t & 1) ? hA : hB);

    dynx_gather_h<<<(NNODES * 8 + 255) / 256, 256, 0, stream>>>(
        dyn_dense + (size_t)t * N * DDIM, dyn_sparse + (size_t)t * N * 2, d_emb, dynx);

    gather_merged<G0DIM><<<(NNODES + 31) / 32, 256, 0, stream>>>(off_t, csr_t, dynx, m1h);

    rowmm64<<<NNODES / 8, 64, 0, stream>>>(
        m1h, gW1 + (size_t)t * G0DIM * HDIM, gb1 + (size_t)t * HDIM, h1h);

    gather_merged<HDIM><<<(NNODES + 15) / 16, 256, 0, stream>>>(off_t, csr_t, h1h, Xh);

    gru_mfma<<<GRUB, 256, 0, stream>>>(
        Xh, hprev, Wcombt + (size_t)t * 512 * 256, bcomb + t * 512,
        Waw, baw, hcur, acch, out, sden, mxv, t == TSTEPS - 1 ? 1 : 0);
  }
}

// Round 23
// 1116.226 us; speedup vs baseline: 1.1506x; 1.0804x over previous
//
#include <hip/hip_runtime.h>
#include <hip/hip_bf16.h>
#include <string.h>

#define NNODES 50000
#define TSTEPS 8
#define NEDGES 800000
#define VVOCAB 1000
#define DDIM 32
#define HDIM 128
#define G0DIM 64
#define H3 384
#define NSB 4          // src blocks: key = dst*NSB + src/SRCBLK
#define SRCBLK 12500
#define NKEY (NNODES * NSB)      // 200000 keys per timestep
#define NBLK 128                 // edge blocks per timestep for the sort
#define EPB 6250                 // edges per block (128*6250 = 800000 exactly)
#define COARSE 391               // coarse bins = key>>9 (max key 199999 -> 390)
#define FINEN 512                // fine keys per coarse bin (key & 511)
#define NSCN (COARSE * NBLK)     // 50048
#define NCHK2 98                 // ceil(NSCN/512)
#define STAGE_CAP 4096           // LDS staging capacity for fine_sort bins

typedef _Float16 v8h __attribute__((ext_vector_type(8)));
typedef float v4f __attribute__((ext_vector_type(4)));

__device__ __forceinline__ float w_decode(unsigned int packed) {
  unsigned short wb = (unsigned short)(packed >> 16);
  _Float16 h;
  __builtin_memcpy(&h, &wb, 2);
  return (float)h;
}

// ---- fast transcendentals (v_exp_f32 + v_rcp_f32), safe for fp16-precision outputs ------
__device__ __forceinline__ float fsigmoid(float v) {
  // rcp(inf)=0 so large |v| is safe
  return __builtin_amdgcn_rcpf(1.f + __expf(-v));
}
__device__ __forceinline__ float ftanh(float x) {
  float xc = fminf(fmaxf(x, -15.f), 15.f);
  float e2 = __expf(2.f * xc);
  return (e2 - 1.f) * __builtin_amdgcn_rcpf(e2 + 1.f);
}

// ============== Atomic-free two-level counting sort (CSR build) ===========================

// A1: per-block LDS histogram over coarse bins -> bh[t][coarse*NBLK + block]
__global__ __launch_bounds__(512) void coarse_hist(const int* __restrict__ edges,
                                                   int* __restrict__ bh) {
  __shared__ int hist[COARSE];
  int t = blockIdx.y, b = blockIdx.x, tid = threadIdx.x;
  for (int i = tid; i < COARSE; i += 512) hist[i] = 0;
  __syncthreads();
  const int* srcp = edges + (size_t)t * 2 * NEDGES + (size_t)b * EPB;
  const int* dstp = srcp + NEDGES;
  for (int i = tid; i < EPB; i += 512) {
    int key = dstp[i] * NSB + srcp[i] / SRCBLK;
    atomicAdd(&hist[key >> 9], 1);
  }
  __syncthreads();
  for (int i = tid; i < COARSE; i += 512) bh[(size_t)t * NSCN + i * NBLK + b] = hist[i];
}

// scan of bh[t][0..NSCN) -> bscan (exclusive), hierarchical
__global__ __launch_bounds__(256) void scan_c1(const int* __restrict__ bh,
                                               int* __restrict__ csum) {
  int bid = blockIdx.x;  // t*NCHK2 + c
  int t = bid / NCHK2, c = bid % NCHK2;
  int tid = threadIdx.x;
  int s = 0;
#pragma unroll
  for (int i = 0; i < 2; ++i) {
    int n = c * 512 + tid + i * 256;
    if (n < NSCN) s += bh[(size_t)t * NSCN + n];
  }
#pragma unroll
  for (int off = 32; off > 0; off >>= 1) s += __shfl_down(s, off, 64);
  __shared__ int wsum[4];
  if ((tid & 63) == 0) wsum[tid >> 6] = s;
  __syncthreads();
  if (tid == 0) csum[bid] = wsum[0] + wsum[1] + wsum[2] + wsum[3];
}

__global__ __launch_bounds__(512) void scan_c2(const int* __restrict__ csum,
                                               int* __restrict__ cbase) {
  int t = blockIdx.x;
  int tid = threadIdx.x;
  __shared__ int buf[512];
  int own = (tid < NCHK2) ? csum[t * NCHK2 + tid] : 0;
  buf[tid] = own;
  __syncthreads();
  for (int d = 1; d < 512; d <<= 1) {
    int v = (tid >= d) ? buf[tid - d] : 0;
    __syncthreads();
    buf[tid] += v;
    __syncthreads();
  }
  if (tid < NCHK2) cbase[t * NCHK2 + tid] = buf[tid] - own;
}

__global__ __launch_bounds__(512) void scan_c3(const int* __restrict__ bh,
                                               const int* __restrict__ cbase,
                                               int* __restrict__ bscan) {
  int bid = blockIdx.x;
  int t = bid / NCHK2, c = bid % NCHK2;
  int tid = threadIdx.x;
  int n = c * 512 + tid;
  int d = (n < NSCN) ? bh[(size_t)t * NSCN + n] : 0;
  __shared__ int buf[512];
  buf[tid] = d;
  __syncthreads();
  for (int s = 1; s < 512; s <<= 1) {
    int v = (tid >= s) ? buf[tid - s] : 0;
    __syncthreads();
    buf[tid] += v;
    __syncthreads();
  }
  if (n < NSCN) bscan[(size_t)t * NSCN + n] = cbase[bid] + buf[tid] - d;
}

// A3: LDS-staged scatter. Block sorts its 6250 edges by coarse bin in LDS, then sweeps
// out linearly: consecutive elements -> consecutive global addresses within bin runs.
__global__ __launch_bounds__(512) void coarse_scatter(
    const int* __restrict__ edges, const float* __restrict__ weights,
    const int* __restrict__ bscan, int2* __restrict__ tmp) {
  __shared__ int hist[COARSE], lstart[COARSE], cur[COARSE], scanb[COARSE];
  __shared__ int2 stage[EPB];  // 50KB
  int t = blockIdx.y, b = blockIdx.x, tid = threadIdx.x;
  for (int i = tid; i < COARSE; i += 512) hist[i] = 0;
  __syncthreads();
  const int* srcp = edges + (size_t)t * 2 * NEDGES + (size_t)b * EPB;
  const int* dstp = srcp + NEDGES;
  const float* wp = weights + (size_t)t * NEDGES + (size_t)b * EPB;
  for (int i = tid; i < EPB; i += 512) {
    int key = dstp[i] * NSB + srcp[i] / SRCBLK;
    atomicAdd(&hist[key >> 9], 1);
  }
  __syncthreads();
  if (tid < COARSE) scanb[tid] = hist[tid];
  __syncthreads();
  for (int d = 1; d < COARSE; d <<= 1) {
    int v = 0;
    if (tid < COARSE && tid >= d) v = scanb[tid - d];
    __syncthreads();
    if (tid < COARSE) scanb[tid] += v;
    __syncthreads();
  }
  if (tid < COARSE) {
    int ls = scanb[tid] - hist[tid];
    lstart[tid] = ls;
    cur[tid] = ls;
  }
  __syncthreads();
  for (int i = tid; i < EPB; i += 512) {
    int src = srcp[i];
    int key = dstp[i] * NSB + src / SRCBLK;
    int coarse = key >> 9, fine = key & 511;
    int lpos = atomicAdd(&cur[coarse], 1);  // LDS atomic
    int2 pk;
    pk.x = src | (fine << 16);
    pk.y = __float_as_int(wp[i]);
    stage[lpos] = pk;
  }
  __syncthreads();
  for (int j = tid; j < EPB; j += 512) {
    int lo = 0, hi = COARSE - 1;
    while (lo < hi) {
      int mid = (lo + hi + 1) >> 1;
      if (lstart[mid] <= j) lo = mid;
      else hi = mid - 1;
    }
    int gpos = bscan[(size_t)t * NSCN + lo * NBLK + b] + (j - lstart[lo]);
    tmp[(size_t)t * NEDGES + gpos] = stage[j];
  }
}

// B: per (t,coarse) bin: LDS counting sort over 512 fine keys -> packed 4B csr + offs.
__global__ __launch_bounds__(512) void fine_sort(
    const int* __restrict__ bscan, const int2* __restrict__ tmp,
    unsigned int* __restrict__ csr, int* __restrict__ offs) {
  __shared__ int fhist[FINEN], fbase[FINEN], fcur[FINEN], buf[FINEN];
  __shared__ unsigned int stage[STAGE_CAP];
  int t = blockIdx.y, coarse = blockIdx.x, tid = threadIdx.x;
  int cb0 = bscan[(size_t)t * NSCN + coarse * NBLK];
  int cb1 = (coarse == COARSE - 1) ? NEDGES : bscan[(size_t)t * NSCN + (coarse + 1) * NBLK];
  int size = cb1 - cb0;
  fhist[tid] = 0;
  fcur[tid] = 0;
  __syncthreads();
  const int2* bin = tmp + (size_t)t * NEDGES + cb0;
  for (int i = tid; i < size; i += 512) {
    int fine = (bin[i].x >> 16) & 511;
    atomicAdd(&fhist[fine], 1);
  }
  __syncthreads();
  buf[tid] = fhist[tid];
  __syncthreads();
  for (int d = 1; d < FINEN; d <<= 1) {
    int v = (tid >= d) ? buf[tid - d] : 0;
    __syncthreads();
    buf[tid] += v;
    __syncthreads();
  }
  fbase[tid] = buf[tid] - fhist[tid];
  int key = coarse * FINEN + tid;
  if (key < NKEY) offs[(size_t)t * (NKEY + 1) + key] = cb0 + fbase[tid];
  if (coarse == COARSE - 1 && tid == 0) offs[(size_t)t * (NKEY + 1) + NKEY] = NEDGES;
  __syncthreads();
  unsigned int* outp = csr + (size_t)t * NEDGES + cb0;
  if (size <= STAGE_CAP) {
    for (int i = tid; i < size; i += 512) {
      int2 p = bin[i];
      int fine = (p.x >> 16) & 511;
      int lr = atomicAdd(&fcur[fine], 1);  // LDS atomic
      _Float16 wh = (_Float16)__int_as_float(p.y);
      unsigned short wb;
      __builtin_memcpy(&wb, &wh, 2);
      stage[fbase[fine] + lr] = (unsigned int)(p.x & 0xFFFF) | ((unsigned int)wb << 16);
    }
    __syncthreads();
    for (int i = tid; i < size; i += 512) outp[i] = stage[i];
  } else {
    for (int i = tid; i < size; i += 512) {
      int2 p = bin[i];
      int fine = (p.x >> 16) & 511;
      int lr = atomicAdd(&fcur[fine], 1);  // LDS atomic
      _Float16 wh = (_Float16)__int_as_float(p.y);
      unsigned short wb;
      __builtin_memcpy(&wb, &wh, 2);
      outp[fbase[fine] + lr] = (unsigned int)(p.x & 0xFFFF) | ((unsigned int)wb << 16);
    }
  }
}

// ============== Gathers (4B packed csr entries) ===========================================

template <int D>
__global__ __launch_bounds__(256) void gather_merged(
    const int* __restrict__ off, const unsigned int* __restrict__ csr,
    const _Float16* __restrict__ x, _Float16* __restrict__ m) {
  const int LPN = D / 8;
  int n = blockIdx.x * (256 / LPN) + threadIdx.x / LPN;
  int l = threadIdx.x % LPN;
  if (n >= NNODES) return;
  int s0 = off[n * NSB], s1 = off[(n + 1) * NSB];
  float a0[8], a1[8];
#pragma unroll
  for (int i = 0; i < 8; ++i) { a0[i] = 0.f; a1[i] = 0.f; }
  int e = s0;
  for (; e + 1 < s1; e += 2) {
    unsigned int eA = csr[e], eB = csr[e + 1];
    v8h xA = *(const v8h*)&x[(size_t)(eA & 0xFFFF) * D + l * 8];
    v8h xB = *(const v8h*)&x[(size_t)(eB & 0xFFFF) * D + l * 8];
    float wA = w_decode(eA), wB = w_decode(eB);
#pragma unroll
    for (int i = 0; i < 8; ++i) {
      a0[i] += wA * (float)xA[i];
      a1[i] += wB * (float)xB[i];
    }
  }
  if (e < s1) {
    unsigned int eA = csr[e];
    v8h xA = *(const v8h*)&x[(size_t)(eA & 0xFFFF) * D + l * 8];
    float wA = w_decode(eA);
#pragma unroll
    for (int i = 0; i < 8; ++i) a0[i] += wA * (float)xA[i];
  }
  v8h r;
#pragma unroll
  for (int i = 0; i < 8; ++i) r[i] = (_Float16)(a0[i] + a1[i]);
  *(v8h*)&m[(size_t)n * D + l * 8] = r;
}

// ============== Dense kernels =============================================================

__global__ __launch_bounds__(384) void fuse_w(
    const float* __restrict__ gW2, const float* __restrict__ Wx, float* __restrict__ Wf) {
  int t = blockIdx.x >> 7;
  int k = blockIdx.x & 127;
  int j = threadIdx.x;
  __shared__ float row[HDIM];
  if (j < HDIM) row[j] = gW2[((size_t)t * HDIM + k) * HDIM + j];
  __syncthreads();
  float acc = 0.f;
#pragma unroll 8
  for (int c = 0; c < HDIM; ++c) acc += row[c] * Wx[c * H3 + j];
  Wf[((size_t)t * HDIM + k) * H3 + j] = acc;
}

__global__ __launch_bounds__(384) void fuse_b(
    const float* __restrict__ gb2, const float* __restrict__ Wx,
    const float* __restrict__ bx, float* __restrict__ bf) {
  int t = blockIdx.x;
  int j = threadIdx.x;
  __shared__ float row[HDIM];
  if (j < HDIM) row[j] = gb2[t * HDIM + j];
  __syncthreads();
  float acc = bx[j];
#pragma unroll 8
  for (int c = 0; c < HDIM; ++c) acc += row[c] * Wx[c * H3 + j];
  bf[t * H3 + j] = acc;
}

// pack combined fp16 weights in MFMA-lane-coalesced layout:
// Bp[t][ks(8)][cg(32)][lr(4)][lj(16)] of v8h, where col = cg*16+lj, k = ks*32 + lr*8 + i.
__global__ __launch_bounds__(256) void pack_wcomb(
    const float* __restrict__ Wf32, const float* __restrict__ Wh,
    _Float16* __restrict__ Bp) {
  int t = blockIdx.x >> 9;
  int col = blockIdx.x & 511;
  int k = threadIdx.x;  // 0..255
  float v;
  if (col < 384) {
    if (k < 128) v = Wf32[((size_t)t * HDIM + k) * H3 + col];
    else v = (col < 256) ? Wh[(size_t)(k - 128) * H3 + col] : 0.f;
  } else {
    v = (k < 128) ? 0.f : Wh[(size_t)(k - 128) * H3 + (col - 128)];
  }
  int cg = col >> 4, lj = col & 15;
  int ks = k >> 5, rem = k & 31, lr = rem >> 3, ki = rem & 7;
  size_t idx = ((((((size_t)t * 8 + ks) * 32 + cg) * 4 + lr) * 16 + lj) * 8) + ki;
  Bp[idx] = (_Float16)v;
}

__global__ __launch_bounds__(512) void pack_bcomb(
    const float* __restrict__ bfb, const float* __restrict__ bh,
    float* __restrict__ bcomb) {
  int t = blockIdx.x;
  int c = threadIdx.x;
  float v;
  if (c < 256) v = bfb[t * H3 + c] + bh[c];
  else if (c < 384) v = bfb[t * H3 + c];
  else v = bh[c - 128];
  bcomb[t * 512 + c] = v;
}

// static encoder + attn init: acch (fp16) = se, sden = 1, mxv = logit
__global__ __launch_bounds__(128) void static_encode_attn_init(
    const float* __restrict__ dense, const int* __restrict__ sparse,
    const float* __restrict__ emb,
    const float* __restrict__ Ws, const float* __restrict__ bs,
    const float* __restrict__ Waw, const float* __restrict__ baw,
    _Float16* __restrict__ acch, float* __restrict__ s, float* __restrict__ mx) {
  int n = blockIdx.x;
  int j = threadIdx.x;
  __shared__ float xs[G0DIM];
  if (j < G0DIM) {
    float v;
    if (j < 16) {
      v = emb[sparse[n * 2 + 0] * 16 + j];
    } else if (j < 32) {
      v = emb[VVOCAB * 16 + sparse[n * 2 + 1] * 16 + (j - 16)];
    } else {
      v = dense[n * DDIM + (j - 32)];
    }
    xs[j] = v;
  }
  __syncthreads();
  float a = bs[j];
#pragma unroll 16
  for (int k = 0; k < G0DIM; ++k) a += xs[k] * Ws[k * HDIM + j];
  a = fmaxf(a, 0.f);
  float v = ftanh(a) * Waw[j];
  __shared__ float red[2];
  int lane = j & 63, wid = j >> 6;
#pragma unroll
  for (int off = 32; off > 0; off >>= 1) v += __shfl_down(v, off, 64);
  if (lane == 0) red[wid] = v;
  __syncthreads();
  acch[(size_t)n * HDIM + j] = (_Float16)a;
  if (j == 0) {
    s[n] = 1.f;
    mx[n] = red[0] + red[1] + baw[0];
  }
}

__global__ __launch_bounds__(256) void dynx_gather_h(
    const float* __restrict__ dense_t, const int* __restrict__ sparse_t,
    const float* __restrict__ emb, _Float16* __restrict__ xout) {
  int idx = blockIdx.x * 256 + threadIdx.x;  // over N*8
  int n = idx >> 3, k8 = idx & 7;
  if (n >= NNODES) return;
  const float* src;
  if (k8 < 2)
    src = &emb[sparse_t[n * 2 + 0] * 16 + k8 * 8];
  else if (k8 < 4)
    src = &emb[VVOCAB * 16 + sparse_t[n * 2 + 1] * 16 + (k8 - 2) * 8];
  else
    src = &dense_t[n * DDIM + (k8 - 4) * 8];
  float4 f0 = *(const float4*)src;
  float4 f1 = *(const float4*)(src + 4);
  v8h v = {(_Float16)f0.x, (_Float16)f0.y, (_Float16)f0.z, (_Float16)f0.w,
           (_Float16)f1.x, (_Float16)f1.y, (_Float16)f1.z, (_Float16)f1.w};
  *(v8h*)&xout[(size_t)n * G0DIM + k8 * 8] = v;
}

__global__ __launch_bounds__(64) void rowmm64(
    const _Float16* __restrict__ x, const float* __restrict__ W,
    const float* __restrict__ b, _Float16* __restrict__ y) {
  const int NB = 8;
  int n0 = blockIdx.x * NB;
  int j = threadIdx.x;
  __shared__ float xT[G0DIM][12];
#pragma unroll
  for (int q = 0; q < NB; ++q) xT[j][q] = (float)x[(size_t)(n0 + q) * G0DIM + j];
  __syncthreads();
  float acc0[NB], acc1[NB];
#pragma unroll
  for (int q = 0; q < NB; ++q) { acc0[q] = 0.f; acc1[q] = 0.f; }
#pragma unroll 4
  for (int k = 0; k < G0DIM; ++k) {
    float4 a = *(const float4*)&xT[k][0];
    float4 c = *(const float4*)&xT[k][4];
    float w0 = W[(size_t)k * HDIM + j];
    float w1 = W[(size_t)k * HDIM + j + 64];
    acc0[0] += a.x * w0; acc0[1] += a.y * w0; acc0[2] += a.z * w0; acc0[3] += a.w * w0;
    acc0[4] += c.x * w0; acc0[5] += c.y * w0; acc0[6] += c.z * w0; acc0[7] += c.w * w0;
    acc1[0] += a.x * w1; acc1[1] += a.y * w1; acc1[2] += a.z * w1; acc1[3] += a.w * w1;
    acc1[4] += c.x * w1; acc1[5] += c.y * w1; acc1[6] += c.z * w1; acc1[7] += c.w * w1;
  }
  float b0 = b[j], b1 = b[j + 64];
#pragma unroll
  for (int q = 0; q < NB; ++q) {
    y[(size_t)(n0 + q) * HDIM + j] = (_Float16)fmaxf(acc0[q] + b0, 0.f);
    y[(size_t)(n0 + q) * HDIM + j + 64] = (_Float16)fmaxf(acc1[q] + b1, 0.f);
  }
}

// MFMA GRU + attention. Coalesced B layout; fp16 h_lds; fast transcendentals.
__global__ __launch_bounds__(256) void gru_mfma(
    const _Float16* __restrict__ Xh, const _Float16* __restrict__ Hp,
    const _Float16* __restrict__ Bt, const float* __restrict__ bcomb,
    const float* __restrict__ Waw, const float* __restrict__ baw,
    _Float16* __restrict__ hout, _Float16* __restrict__ acch,
    float* __restrict__ outf, float* __restrict__ sden, float* __restrict__ mxv,
    int last) {
  const int AST = 264;
  __shared__ _Float16 A_lds[32 * AST];
  __shared__ _Float16 h_lds[32 * 132];
  __shared__ float lg[32], facs[32], ps[32], sdn[32];
  int tid = threadIdx.x;
  int w = tid >> 6, lane = tid & 63;
  int n0 = blockIdx.x * 32;

#pragma unroll
  for (int i = 0; i < 4; ++i) {
    int cid = tid + i * 256;
    int row = cid >> 5, ch = cid & 31;
    int n = n0 + row;
    v8h v = {(_Float16)0, (_Float16)0, (_Float16)0, (_Float16)0,
             (_Float16)0, (_Float16)0, (_Float16)0, (_Float16)0};
    if (n < NNODES) {
      if (ch < 16) v = *(const v8h*)&Xh[(size_t)n * HDIM + ch * 8];
      else if (Hp) v = *(const v8h*)&Hp[(size_t)n * HDIM + (ch - 16) * 8];
    }
    *(v8h*)&A_lds[row * AST + ch * 8] = v;
  }
  __syncthreads();

  int lj = lane & 15, lr = lane >> 4;
  const v8h* Bp = (const v8h*)Bt;  // [ks][cg][lr][lj] fragments, lane-coalesced
  v4f accf[2][8];
#pragma unroll
  for (int m = 0; m < 2; ++m)
#pragma unroll
    for (int f = 0; f < 8; ++f) accf[m][f] = (v4f){0.f, 0.f, 0.f, 0.f};

  for (int ks = 0; ks < 8; ++ks) {
    v8h a0 = *(const v8h*)&A_lds[lj * AST + ks * 32 + lr * 8];
    v8h a1 = *(const v8h*)&A_lds[(16 + lj) * AST + ks * 32 + lr * 8];
#pragma unroll
    for (int g = 0; g < 4; ++g)
#pragma unroll
      for (int p = 0; p < 2; ++p) {
        int cg = g * 8 + w * 2 + p;
        v8h b = Bp[((ks * 32 + cg) * 4 + lr) * 16 + lj];
        accf[0][g * 2 + p] =
            __builtin_amdgcn_mfma_f32_16x16x32_f16(a0, b, accf[0][g * 2 + p], 0, 0, 0);
        accf[1][g * 2 + p] =
            __builtin_amdgcn_mfma_f32_16x16x32_f16(a1, b, accf[1][g * 2 + p], 0, 0, 0);
      }
  }

#pragma unroll
  for (int p = 0; p < 2; ++p) {
    int j = (w * 2 + p) * 16 + lj;
    float br = bcomb[j], bz = bcomb[128 + j], bxn = bcomb[256 + j], bhn = bcomb[384 + j];
#pragma unroll
    for (int m = 0; m < 2; ++m)
#pragma unroll
      for (int reg = 0; reg < 4; ++reg) {
        int row = m * 16 + lr * 4 + reg;
        float r = fsigmoid(accf[m][0 + p][reg] + br);
        float z = fsigmoid(accf[m][2 + p][reg] + bz);
        float hp = (float)A_lds[row * AST + 128 + j];
        float nc = ftanh(accf[m][4 + p][reg] + bxn + r * (accf[m][6 + p][reg] + bhn));
        h_lds[row * 132 + j] = (_Float16)((1.f - z) * nc + z * hp);
      }
  }
  __syncthreads();

  float waw0 = Waw[lane], waw1 = Waw[lane + 64];
#pragma unroll
  for (int q = 0; q < 8; ++q) {
    int row = w * 8 + q;
    float v = ftanh((float)h_lds[row * 132 + lane]) * waw0 +
              ftanh((float)h_lds[row * 132 + lane + 64]) * waw1;
#pragma unroll
    for (int off = 32; off > 0; off >>= 1) v += __shfl_down(v, off, 64);
    if (lane == 0) lg[row] = v;
  }
  __syncthreads();
  if (tid < 32) {
    int n = n0 + tid;
    if (n < NNODES) {
      float l = lg[tid] + baw[0];
      float m = mxv[n];
      float mnew = fmaxf(m, l);
      float fac = __expf(m - mnew);
      float pp = __expf(l - mnew);
      facs[tid] = fac;
      ps[tid] = pp;
      float snew = sden[n] * fac + pp;
      sdn[tid] = snew;
      sden[n] = snew;
      mxv[n] = mnew;
    }
  }
  __syncthreads();
  if (last) {
#pragma unroll
    for (int i = 0; i < 16; ++i) {
      int idx = tid + i * 256;
      int row = idx >> 7, col = idx & 127;
      int n = n0 + row;
      if (n < NNODES) {
        float hv = (float)h_lds[row * 132 + col];
        size_t o = (size_t)n * HDIM + col;
        float av = (float)acch[o];
        outf[o] = (av * facs[row] + ps[row] * hv) / sdn[row];
      }
    }
  } else {
#pragma unroll
    for (int i = 0; i < 16; ++i) {
      int idx = tid + i * 256;
      int row = idx >> 7, col = idx & 127;
      int n = n0 + row;
      if (n < NNODES) {
        float hv = (float)h_lds[row * 132 + col];
        size_t o = (size_t)n * HDIM + col;
        float av = (float)acch[o];
        acch[o] = (_Float16)(av * facs[row] + ps[row] * hv);
        hout[o] = (_Float16)hv;
      }
    }
  }
}

extern "C" void kernel_launch(void* const* d_in, const int* in_sizes, int n_in,
                              void* d_out, int out_size, void* d_ws, size_t ws_size,
                              hipStream_t stream) {
  const float* static_dense = (const float*)d_in[0];
  const int*   static_sparse = (const int*)d_in[1];
  const float* dyn_dense = (const float*)d_in[2];
  const int*   dyn_sparse = (const int*)d_in[3];
  const int*   edges = (const int*)d_in[4];
  const float* weights = (const float*)d_in[5];
  const float* s_emb = (const float*)d_in[6];
  const float* d_emb = (const float*)d_in[7];
  const float* Ws = (const float*)d_in[8];
  const float* bs = (const float*)d_in[9];
  const float* gW1 = (const float*)d_in[10];
  const float* gb1 = (const float*)d_in[11];
  const float* gW2 = (const float*)d_in[12];
  const float* gb2 = (const float*)d_in[13];
  const float* Wx = (const float*)d_in[14];
  const float* Wh = (const float*)d_in[15];
  const float* bx = (const float*)d_in[16];
  const float* bh_in = (const float*)d_in[17];
  const float* Waw = (const float*)d_in[18];
  const float* baw = (const float*)d_in[19];
  float* out = (float*)d_out;  // final fp32 output [N,128], written by last gru_mfma

  const size_t N = NNODES;
  char* p = (char*)d_ws;
  auto alloc = [&](size_t bytes) { char* r = p; p += (bytes + 255) & ~(size_t)255; return r; };
  float*     sden   = (float*)alloc(N * 4);
  float*     mxv    = (float*)alloc(N * 4);
  _Float16*  acch   = (_Float16*)alloc(N * HDIM * 2);      // fp16 attention accumulator
  // Big block: loop buffers; tmp (51.2MB) aliases it — tmp is fully consumed by fine_sort
  // BEFORE the loop's first write into any of these (stream order).
  char*      big    = alloc(64UL * 1024 * 1024);
  _Float16*  hA     = (_Float16*)big;                      // 12.8MB
  _Float16*  hB     = hA + N * HDIM;                       // 12.8MB
  _Float16*  dynx   = hB + N * HDIM;                       // 6.4MB
  _Float16*  m1h    = dynx + N * G0DIM;                    // 6.4MB
  _Float16*  h1h    = m1h + N * G0DIM;                     // 12.8MB
  _Float16*  Xh     = h1h + N * HDIM;                      // 12.8MB
  int2*      tmp    = (int2*)big;                          // 51.2MB alias
  float*     Wf32   = (float*)alloc((size_t)TSTEPS * HDIM * H3 * 4);
  _Float16*  Wcombt = (_Float16*)alloc((size_t)TSTEPS * 512 * 256 * 2);
  float*     bfb    = (float*)alloc((size_t)TSTEPS * H3 * 4);
  float*     bcomb  = (float*)alloc((size_t)TSTEPS * 512 * 4);
  int*       bhist  = (int*)alloc((size_t)TSTEPS * NSCN * 4);   // 1.6MB
  int*       bscan  = (int*)alloc((size_t)TSTEPS * NSCN * 4);   // 1.6MB
  int*       csum   = (int*)alloc((size_t)TSTEPS * NCHK2 * 4);
  int*       cbase  = (int*)alloc((size_t)TSTEPS * NCHK2 * 4);
  int*       offs   = (int*)alloc((size_t)TSTEPS * (NKEY + 1) * 4);
  unsigned int* csr = (unsigned int*)alloc((size_t)TSTEPS * NEDGES * 4);  // 25.6MB packed

  // ---- atomic-free two-level counting sort (all timesteps) ----
  coarse_hist<<<dim3(NBLK, TSTEPS), 512, 0, stream>>>(edges, bhist);
  scan_c1<<<TSTEPS * NCHK2, 256, 0, stream>>>(bhist, csum);
  scan_c2<<<TSTEPS, 512, 0, stream>>>(csum, cbase);
  scan_c3<<<TSTEPS * NCHK2, 512, 0, stream>>>(bhist, cbase, bscan);
  coarse_scatter<<<dim3(NBLK, TSTEPS), 512, 0, stream>>>(edges, weights, bscan, tmp);
  fine_sort<<<dim3(COARSE, TSTEPS), 512, 0, stream>>>(bscan, tmp, csr, offs);

  // ---- weight/bias preprocessing ----
  fuse_w<<<TSTEPS * HDIM, H3, 0, stream>>>(gW2, Wx, Wf32);
  fuse_b<<<TSTEPS, H3, 0, stream>>>(gb2, Wx, bx, bfb);
  pack_wcomb<<<TSTEPS * 512, 256, 0, stream>>>(Wf32, Wh, Wcombt);
  pack_bcomb<<<TSTEPS, 512, 0, stream>>>(bfb, bh_in, bcomb);

  static_encode_attn_init<<<NNODES, 128, 0, stream>>>(
      static_dense, static_sparse, s_emb, Ws, bs, Waw, baw, acch, sden, mxv);

  const int GRUB = (NNODES + 31) / 32;
  for (int t = 0; t < TSTEPS; ++t) {
    const int* off_t = offs + (size_t)t * (NKEY + 1);
    const unsigned int* csr_t = csr + (size_t)t * NEDGES;
    _Float16* hcur = (t & 1) ? hB : hA;
    const _Float16* hprev = (t == 0) ? nullptr : ((t & 1) ? hA : hB);

    dynx_gather_h<<<(NNODES * 8 + 255) / 256, 256, 0, stream>>>(
        dyn_dense + (size_t)t * N * DDIM, dyn_sparse + (size_t)t * N * 2, d_emb, dynx);

    gather_merged<G0DIM><<<(NNODES + 31) / 32, 256, 0, stream>>>(off_t, csr_t, dynx, m1h);

    rowmm64<<<NNODES / 8, 64, 0, stream>>>(
        m1h, gW1 + (size_t)t * G0DIM * HDIM, gb1 + (size_t)t * HDIM, h1h);

    gather_merged<HDIM><<<(NNODES + 15) / 16, 256, 0, stream>>>(off_t, csr_t, h1h, Xh);

    gru_mfma<<<GRUB, 256, 0, stream>>>(
        Xh, hprev, Wcombt + (size_t)t * 512 * 256, bcomb + t * 512,
        Waw, baw, hcur, acch, out, sden, mxv, t == TSTEPS - 1 ? 1 : 0);
  }
}